// Round 1
// baseline (282.205 us; speedup 1.0000x reference)
//
#include <hip/hip_runtime.h>

// DeepQNetwork mixture-of-experts: B rows, each row runs 1 of NE expert MLPs
// (DIM->HID, 4x HID->HID, HID->NA) selected by rm_state. Strategy:
//  1) bucket rows by expert (LDS-aggregated atomic scatter),
//  2) per-block single-expert compute: weights wave-uniform -> s_load,
//     activations in LDS (stride 65 -> conflict-free) for dynamic-k indexing,
//     accumulators statically indexed in VGPRs.

#define NE   8
#define DIM  256
#define HID  64
#define NA   18
#define TILE 128   // rows per compute block (= block threads)

__global__ void zero_ws_kernel(int* cursors) {
    int t = threadIdx.x;
    if (t < NE) cursors[t] = 0;
}

// One thread per row: block-aggregated bucket scatter.
__global__ void scatter_kernel(const int* __restrict__ rm, int* cursors,
                               int* perm, int B) {
    __shared__ int lcnt[NE];
    __shared__ int lbase[NE];
    const int t = threadIdx.x;
    if (t < NE) lcnt[t] = 0;
    __syncthreads();
    const int i = blockIdx.x * blockDim.x + t;
    const int e = rm[i];
    const int r = atomicAdd(&lcnt[e], 1);     // local rank within block
    __syncthreads();
    if (t < NE) lbase[t] = atomicAdd(&cursors[t], lcnt[t]);
    __syncthreads();
    perm[e * B + lbase[e] + r] = i;
}

__device__ __forceinline__ void hidden_layer(const float* __restrict__ Wp,
                                             const float* __restrict__ bp,
                                             float* __restrict__ hrow) {
    float acc[HID];
    #pragma unroll
    for (int j = 0; j < HID; ++j) acc[j] = bp[j];
    #pragma unroll 1
    for (int k = 0; k < HID; ++k) {
        const float hk = hrow[k];                 // LDS read, dynamic k (1 per 64 FMA)
        const float* wrow = Wp + k * HID;         // wave-uniform -> s_load
        #pragma unroll
        for (int j = 0; j < HID; ++j) acc[j] = fmaf(hk, wrow[j], acc[j]);
    }
    #pragma unroll
    for (int j = 0; j < HID; ++j) hrow[j] = fmaxf(acc[j], 0.0f);
}

__global__ __launch_bounds__(TILE) void mlp_kernel(
    const float* __restrict__ x,
    const int* __restrict__ cursors, const int* __restrict__ perm,
    const float* __restrict__ W1, const float* __restrict__ b1,
    const float* __restrict__ W2, const float* __restrict__ b2,
    const float* __restrict__ W3, const float* __restrict__ b3,
    const float* __restrict__ W4, const float* __restrict__ b4,
    const float* __restrict__ W5, const float* __restrict__ b5,
    const float* __restrict__ W6, const float* __restrict__ b6,
    float* __restrict__ out, int B)
{
    // stride 65: bank = (t + k) mod 32 -> 2 lanes/bank = conflict-free
    __shared__ float hbuf[TILE * (HID + 1)];

    const int tilesPerE = B / TILE;
    const int e    = blockIdx.x / tilesPerE;     // wave-uniform
    const int tile = blockIdx.x % tilesPerE;
    const int cnt  = cursors[e];
    if (tile * TILE >= cnt) return;              // empty tile for this expert
    const int t  = threadIdx.x;
    const int li = tile * TILE + t;
    if (li >= cnt) return;                       // partial tail tile (no barriers below)
    const int row = perm[e * B + li];

    const float* __restrict__ W1p = W1 + e * DIM * HID;
    const float* __restrict__ b1p = b1 + e * HID;
    const float* __restrict__ W2p = W2 + e * HID * HID;
    const float* __restrict__ b2p = b2 + e * HID;
    const float* __restrict__ W3p = W3 + e * HID * HID;
    const float* __restrict__ b3p = b3 + e * HID;
    const float* __restrict__ W4p = W4 + e * HID * HID;
    const float* __restrict__ b4p = b4 + e * HID;
    const float* __restrict__ W5p = W5 + e * HID * HID;
    const float* __restrict__ b5p = b5 + e * HID;
    const float* __restrict__ W6p = W6 + e * HID * NA;
    const float* __restrict__ b6p = b6 + e * NA;

    float* __restrict__ hrow = &hbuf[t * (HID + 1)];

    // ---- layer 1: [DIM] x [DIM,HID] ----
    {
        float acc[HID];
        #pragma unroll
        for (int j = 0; j < HID; ++j) acc[j] = b1p[j];
        const float* xr = x + (size_t)row * DIM;
        #pragma unroll 1
        for (int k0 = 0; k0 < DIM; k0 += 4) {
            const float4 xv = *reinterpret_cast<const float4*>(xr + k0);
            const float xs[4] = {xv.x, xv.y, xv.z, xv.w};
            #pragma unroll
            for (int kk = 0; kk < 4; ++kk) {
                const float* wrow = W1p + (k0 + kk) * HID;   // uniform -> s_load
                #pragma unroll
                for (int j = 0; j < HID; ++j)
                    acc[j] = fmaf(xs[kk], wrow[j], acc[j]);
            }
        }
        #pragma unroll
        for (int j = 0; j < HID; ++j) hrow[j] = fmaxf(acc[j], 0.0f);
    }

    // ---- layers 2..5: [HID] x [HID,HID] ----
    hidden_layer(W2p, b2p, hrow);
    hidden_layer(W3p, b3p, hrow);
    hidden_layer(W4p, b4p, hrow);
    hidden_layer(W5p, b5p, hrow);

    // ---- layer 6: [HID] x [HID,NA], no relu ----
    {
        float acc[NA];
        #pragma unroll
        for (int a = 0; a < NA; ++a) acc[a] = b6p[a];
        #pragma unroll 1
        for (int k = 0; k < HID; ++k) {
            const float hk = hrow[k];
            const float* wrow = W6p + k * NA;
            #pragma unroll
            for (int a = 0; a < NA; ++a) acc[a] = fmaf(hk, wrow[a], acc[a]);
        }
        float* orow = out + (size_t)row * NA;
        #pragma unroll
        for (int a = 0; a < NA; ++a) orow[a] = acc[a];
    }
}

extern "C" void kernel_launch(void* const* d_in, const int* in_sizes, int n_in,
                              void* d_out, int out_size, void* d_ws, size_t ws_size,
                              hipStream_t stream) {
    const float* x  = (const float*)d_in[0];
    const int*   rm = (const int*)d_in[1];
    const float* W1 = (const float*)d_in[2];   const float* b1 = (const float*)d_in[3];
    const float* W2 = (const float*)d_in[4];   const float* b2 = (const float*)d_in[5];
    const float* W3 = (const float*)d_in[6];   const float* b3 = (const float*)d_in[7];
    const float* W4 = (const float*)d_in[8];   const float* b4 = (const float*)d_in[9];
    const float* W5 = (const float*)d_in[10];  const float* b5 = (const float*)d_in[11];
    const float* W6 = (const float*)d_in[12];  const float* b6 = (const float*)d_in[13];
    float* out = (float*)d_out;

    const int B = in_sizes[1];                 // 65536

    // ws layout: cursors[NE] | perm[NE * B]   (~2 MiB; ws re-poisoned each call)
    int* cursors = (int*)d_ws;
    int* perm    = cursors + NE;

    zero_ws_kernel<<<1, 64, 0, stream>>>(cursors);
    scatter_kernel<<<B / 256, 256, 0, stream>>>(rm, cursors, perm, B);
    mlp_kernel<<<NE * (B / TILE), TILE, 0, stream>>>(
        x, cursors, perm,
        W1, b1, W2, b2, W3, b3, W4, b4, W5, b5, W6, b6,
        out, B);
}

// Round 2
// 153.948 us; speedup vs baseline: 1.8331x; 1.8331x over previous
//
#include <hip/hip_runtime.h>

// DeepQNetwork MoE as a sorted grouped GEMM with split-bf16 MFMA.
// Pipeline: histo (ballot) -> scan (prefix, tile ranges) -> scatter (ballot rank)
//           -> prep (weights -> bf16 hi/lo MFMA B-fragments in ws)
//           -> mlp  (64 rows/block, 1 expert/block, mfma_f32_16x16x32_bf16 x3 split)

#define NE   8
#define DIM  256
#define HID  64
#define NA   18

typedef __attribute__((ext_vector_type(8))) short short8;
typedef __attribute__((ext_vector_type(4))) float f32x4;
#define MFMA __builtin_amdgcn_mfma_f32_16x16x32_bf16

// ---------- bf16 split helpers (round-to-nearest-even) ----------
__device__ __forceinline__ unsigned short f2bf(float f) {
    unsigned u = __builtin_bit_cast(unsigned, f);
    u += 0x7fff + ((u >> 16) & 1);
    return (unsigned short)(u >> 16);
}
__device__ __forceinline__ float bf2f(unsigned short h) {
    unsigned u = ((unsigned)h) << 16;
    return __builtin_bit_cast(float, u);
}
__device__ __forceinline__ void split8(const float* xs, short8& hi, short8& lo) {
    #pragma unroll
    for (int j = 0; j < 8; ++j) {
        unsigned short h = f2bf(xs[j]);
        hi[j] = (short)h;
        lo[j] = (short)f2bf(xs[j] - bf2f(h));
    }
}

// ---------- phase A: per-256-block expert histogram (no atomics) ----------
__global__ __launch_bounds__(256) void histo_kernel(const int* __restrict__ rm,
                                                    int* __restrict__ hist) {
    __shared__ int wc[4][NE];
    const int t = threadIdx.x, w = t >> 6, l = t & 63;
    const int e = rm[blockIdx.x * 256 + t];
    #pragma unroll
    for (int q = 0; q < NE; ++q) {
        unsigned long long m = __ballot(e == q);
        if (l == 0) wc[w][q] = __popcll(m);
    }
    __syncthreads();
    if (t < NE) hist[blockIdx.x * NE + t] = wc[0][t] + wc[1][t] + wc[2][t] + wc[3][t];
}

// ---------- phase B: scan over 256 block-histograms, emit bases + meta ----------
// meta[0..7]=counts  meta[8..16]=expertStart  meta[17..25]=tileStart
__global__ __launch_bounds__(256) void scan_kernel(const int* __restrict__ hist,
                                                   int* __restrict__ base,
                                                   int* __restrict__ meta) {
    __shared__ int s[256][NE];
    __shared__ int tot[NE];
    const int t = threadIdx.x;
    int v[NE], own[NE];
    #pragma unroll
    for (int e = 0; e < NE; ++e) { own[e] = hist[t * NE + e]; v[e] = own[e]; }
    for (int off = 1; off < 256; off <<= 1) {
        #pragma unroll
        for (int e = 0; e < NE; ++e) s[t][e] = v[e];
        __syncthreads();
        if (t >= off) {
            #pragma unroll
            for (int e = 0; e < NE; ++e) v[e] += s[t - off][e];
        }
        __syncthreads();
    }
    if (t == 255) {
        #pragma unroll
        for (int e = 0; e < NE; ++e) tot[e] = v[e];
    }
    __syncthreads();
    int es[NE + 1]; es[0] = 0;
    #pragma unroll
    for (int e = 0; e < NE; ++e) es[e + 1] = es[e] + tot[e];
    #pragma unroll
    for (int e = 0; e < NE; ++e) base[t * NE + e] = es[e] + v[e] - own[e];
    if (t == 0) {
        #pragma unroll
        for (int e = 0; e < NE; ++e) meta[e] = tot[e];
        #pragma unroll
        for (int e = 0; e <= NE; ++e) meta[8 + e] = es[e];
        int ts = 0; meta[17] = 0;
        #pragma unroll
        for (int e = 0; e < NE; ++e) { ts += (tot[e] + 63) >> 6; meta[17 + e + 1] = ts; }
    }
}

// ---------- phase C: rank-and-scatter (no atomics) ----------
__global__ __launch_bounds__(256) void scatter_kernel(const int* __restrict__ rm,
                                                      const int* __restrict__ base,
                                                      int* __restrict__ perm) {
    __shared__ int wc[4][NE];
    __shared__ int wb[4][NE];
    const int t = threadIdx.x, w = t >> 6, l = t & 63;
    const int i = blockIdx.x * 256 + t;
    const int e = rm[i];
    const unsigned long long ltm = (1ull << l) - 1ull;
    int rank = 0;
    #pragma unroll
    for (int q = 0; q < NE; ++q) {
        unsigned long long m = __ballot(e == q);
        if (e == q) rank = __popcll(m & ltm);
        if (l == 0) wc[w][q] = __popcll(m);
    }
    __syncthreads();
    if (t < 32) {
        int ww = t >> 3, q = t & 7;
        int b = base[blockIdx.x * NE + q];
        for (int p = 0; p < ww; ++p) b += wc[p][q];
        wb[ww][q] = b;
    }
    __syncthreads();
    perm[wb[w][e] + rank] = i;
}

// ---------- weight fragmentation: fp32 -> bf16 hi/lo, MFMA B-frag order ----------
// frag idx within expert-layer: ((ks*NNT + nt)*64 + lane)*8 + j
// value = W[k][n],  k = ks*32 + (lane>>4)*8 + j,  n = nt*16 + (lane&15)
__global__ __launch_bounds__(256) void prep_kernel(
    const float* __restrict__ W1, const float* __restrict__ W2,
    const float* __restrict__ W3, const float* __restrict__ W4,
    const float* __restrict__ W5, const float* __restrict__ W6,
    short* __restrict__ W1H, short* __restrict__ W1L,
    short* __restrict__ W2H, short* __restrict__ W2L,
    short* __restrict__ W3H, short* __restrict__ W3L,
    short* __restrict__ W4H, short* __restrict__ W4L,
    short* __restrict__ W5H, short* __restrict__ W5L,
    short* __restrict__ W6H, short* __restrict__ W6L) {
    const int idx = blockIdx.x * 256 + threadIdx.x;
    float v; short* H; short* L; int sidx;
    if (idx < 131072) {                       // W1: 8e x 8ks x 4nt x 64l x 8j
        int e = idx >> 14, r = idx & 16383;
        int ks = r >> 11, nt = (r >> 9) & 3, l = (r >> 3) & 63, j = r & 7;
        int k = ks * 32 + ((l >> 4) << 3) + j, n = (nt << 4) + (l & 15);
        v = W1[(e * DIM + k) * HID + n];
        H = W1H; L = W1L; sidx = idx;
    } else if (idx < 131072 + 4 * 32768) {    // W2..W5: 8e x 2ks x 4nt x 64l x 8j
        int layer = (idx - 131072) >> 15;
        int local = (idx - 131072) & 32767;
        int e = local >> 12, r = local & 4095;
        int ks = r >> 11, nt = (r >> 9) & 3, l = (r >> 3) & 63, j = r & 7;
        int k = ks * 32 + ((l >> 4) << 3) + j, n = (nt << 4) + (l & 15);
        const float* W = (layer == 0) ? W2 : (layer == 1) ? W3 : (layer == 2) ? W4 : W5;
        v = W[(e * HID + k) * HID + n];
        H = (layer == 0) ? W2H : (layer == 1) ? W3H : (layer == 2) ? W4H : W5H;
        L = (layer == 0) ? W2L : (layer == 1) ? W3L : (layer == 2) ? W4L : W5L;
        sidx = local;
    } else if (idx < 131072 + 4 * 32768 + 16384) {  // W6: 8e x 2ks x 2nt x 64l x 8j (N pad->32)
        int local = idx - (131072 + 4 * 32768);
        int e = local >> 11, r = local & 2047;
        int ks = r >> 10, nt = (r >> 9) & 1, l = (r >> 3) & 63, j = r & 7;
        int k = ks * 32 + ((l >> 4) << 3) + j, n = (nt << 4) + (l & 15);
        v = (n < NA) ? W6[(e * HID + k) * NA + n] : 0.0f;
        H = W6H; L = W6L; sidx = local;
    } else return;
    unsigned short h = f2bf(v);
    H[sidx] = (short)h;
    L[sidx] = (short)f2bf(v - bf2f(h));
}

// ---------- MFMA MLP ----------
// K=64 layer: A from per-wave LDS h[16][68], B-frags from ws (hi/lo), 3-term split.
template <int NT>
__device__ __forceinline__ void gemm_k64(const float* hsrc, int l,
                                         const short* __restrict__ WH,
                                         const short* __restrict__ WL,
                                         f32x4* acc) {
    const int lg = l >> 4, lr = l & 15;
    #pragma unroll
    for (int ks = 0; ks < 2; ++ks) {
        const float* ap = hsrc + lr * 68 + ks * 32 + lg * 8;
        float4 v0 = *(const float4*)(ap);
        float4 v1 = *(const float4*)(ap + 4);
        float xs[8] = {v0.x, v0.y, v0.z, v0.w, v1.x, v1.y, v1.z, v1.w};
        short8 ahi, alo; split8(xs, ahi, alo);
        #pragma unroll
        for (int nt = 0; nt < NT; ++nt) {
            const short8 bhi = *(const short8*)(WH + ((ks * NT + nt) * 64 + l) * 8);
            const short8 blo = *(const short8*)(WL + ((ks * NT + nt) * 64 + l) * 8);
            acc[nt] = MFMA(ahi, bhi, acc[nt], 0, 0, 0);
            acc[nt] = MFMA(alo, bhi, acc[nt], 0, 0, 0);
            acc[nt] = MFMA(ahi, blo, acc[nt], 0, 0, 0);
        }
    }
}

template <int NT, bool RELU>
__device__ __forceinline__ void finish_to_lds(float* hdst, int l,
                                              const float* __restrict__ bias,
                                              f32x4* acc) {
    const int lg = l >> 4, lr = l & 15;
    #pragma unroll
    for (int nt = 0; nt < NT; ++nt) {
        float bv = bias[nt * 16 + lr];
        #pragma unroll
        for (int r = 0; r < 4; ++r) {
            float v = acc[nt][r] + bv;
            if (RELU) v = fmaxf(v, 0.0f);
            hdst[(lg * 4 + r) * 68 + nt * 16 + lr] = v;   // D: row=(l>>4)*4+r, col=l&15 (m89)
        }
    }
}

__global__ __launch_bounds__(256) void mlp_mfma(
    const float* __restrict__ x, const int* __restrict__ perm,
    const int* __restrict__ meta,
    const short* __restrict__ W1H, const short* __restrict__ W1L,
    const short* __restrict__ W2H, const short* __restrict__ W2L,
    const short* __restrict__ W3H, const short* __restrict__ W3L,
    const short* __restrict__ W4H, const short* __restrict__ W4L,
    const short* __restrict__ W5H, const short* __restrict__ W5L,
    const short* __restrict__ W6H, const short* __restrict__ W6L,
    const float* __restrict__ b1, const float* __restrict__ b2,
    const float* __restrict__ b3, const float* __restrict__ b4,
    const float* __restrict__ b5, const float* __restrict__ b6,
    float* __restrict__ out) {
    __shared__ __align__(16) float hbuf[4][16][68];
    const int blk = blockIdx.x;
    if (blk >= meta[17 + NE]) return;        // past last tile
    int e = 0;
    #pragma unroll 1
    while (blk >= meta[17 + e + 1]) ++e;
    const int lt = blk - meta[17 + e];
    const int cnt = meta[e];
    const int pbase = meta[8 + e];
    const int t = threadIdx.x, w = t >> 6, l = t & 63;
    const int lg = l >> 4, lr = l & 15;
    const int li = lt * 64 + w * 16 + lr;
    const int row = perm[pbase + min(li, cnt - 1)];
    float* hw = &hbuf[w][0][0];
    const f32x4 zero = {0.0f, 0.0f, 0.0f, 0.0f};

    // ---- layer 1: x[row][256] @ W1 -> h[16][64] ----
    {
        f32x4 acc[4] = {zero, zero, zero, zero};
        const float* xr = x + (size_t)row * DIM + lg * 8;
        const short* WHp = W1H + (size_t)e * 32 * 512 + l * 8;
        const short* WLp = W1L + (size_t)e * 32 * 512 + l * 8;
        #pragma unroll
        for (int ks = 0; ks < 8; ++ks) {
            float4 v0 = *(const float4*)(xr + ks * 32);
            float4 v1 = *(const float4*)(xr + ks * 32 + 4);
            float xs[8] = {v0.x, v0.y, v0.z, v0.w, v1.x, v1.y, v1.z, v1.w};
            short8 ahi, alo; split8(xs, ahi, alo);
            #pragma unroll
            for (int nt = 0; nt < 4; ++nt) {
                const short8 bhi = *(const short8*)(WHp + (ks * 4 + nt) * 512);
                const short8 blo = *(const short8*)(WLp + (ks * 4 + nt) * 512);
                acc[nt] = MFMA(ahi, bhi, acc[nt], 0, 0, 0);
                acc[nt] = MFMA(alo, bhi, acc[nt], 0, 0, 0);
                acc[nt] = MFMA(ahi, blo, acc[nt], 0, 0, 0);
            }
        }
        finish_to_lds<4, true>(hw, l, b1 + e * HID, acc);
    }
    // ---- layers 2..5 ----
    {
        f32x4 acc[4] = {zero, zero, zero, zero};
        gemm_k64<4>(hw, l, W2H + e * 8 * 512, W2L + e * 8 * 512, acc);
        finish_to_lds<4, true>(hw, l, b2 + e * HID, acc);
    }
    {
        f32x4 acc[4] = {zero, zero, zero, zero};
        gemm_k64<4>(hw, l, W3H + e * 8 * 512, W3L + e * 8 * 512, acc);
        finish_to_lds<4, true>(hw, l, b3 + e * HID, acc);
    }
    {
        f32x4 acc[4] = {zero, zero, zero, zero};
        gemm_k64<4>(hw, l, W4H + e * 8 * 512, W4L + e * 8 * 512, acc);
        finish_to_lds<4, true>(hw, l, b4 + e * HID, acc);
    }
    {
        f32x4 acc[4] = {zero, zero, zero, zero};
        gemm_k64<4>(hw, l, W5H + e * 8 * 512, W5L + e * 8 * 512, acc);
        finish_to_lds<4, true>(hw, l, b5 + e * HID, acc);
    }
    // ---- layer 6 + scatter store ----
    {
        f32x4 acc[2] = {zero, zero};
        gemm_k64<2>(hw, l, W6H + e * 4 * 512, W6L + e * 4 * 512, acc);
        const float* b6p = b6 + e * NA;
        #pragma unroll
        for (int r = 0; r < 4; ++r) {
            const int drow = lg * 4 + r;
            const int rs = __shfl(row, drow, 64);         // global row id of D-row
            const bool valid = (lt * 64 + w * 16 + drow) < cnt;
            #pragma unroll
            for (int nt = 0; nt < 2; ++nt) {
                const int col = nt * 16 + lr;
                if (valid && col < NA)
                    out[(size_t)rs * NA + col] = acc[nt][r] + b6p[col];
            }
        }
    }
}

extern "C" void kernel_launch(void* const* d_in, const int* in_sizes, int n_in,
                              void* d_out, int out_size, void* d_ws, size_t ws_size,
                              hipStream_t stream) {
    const float* x  = (const float*)d_in[0];
    const int*   rm = (const int*)d_in[1];
    const float* W1 = (const float*)d_in[2];   const float* b1 = (const float*)d_in[3];
    const float* W2 = (const float*)d_in[4];   const float* b2 = (const float*)d_in[5];
    const float* W3 = (const float*)d_in[6];   const float* b3 = (const float*)d_in[7];
    const float* W4 = (const float*)d_in[8];   const float* b4 = (const float*)d_in[9];
    const float* W5 = (const float*)d_in[10];  const float* b5 = (const float*)d_in[11];
    const float* W6 = (const float*)d_in[12];  const float* b6 = (const float*)d_in[13];
    float* out = (float*)d_out;

    const int B = in_sizes[1];                 // 65536
    const int nblk = B / 256;                  // 256

    // ws layout (ints then shorts, all 16B-aligned):
    int* hist = (int*)d_ws;                    // nblk*8
    int* base = hist + nblk * NE;              // nblk*8
    int* meta = base + nblk * NE;              // 32
    int* perm = meta + 32;                     // B
    short* W1H = (short*)(perm + B);           // 131072 each
    short* W1L = W1H + 131072;
    short* W2H = W1L + 131072;  short* W2L = W2H + 32768;
    short* W3H = W2L + 32768;   short* W3L = W3H + 32768;
    short* W4H = W3L + 32768;   short* W4L = W4H + 32768;
    short* W5H = W4L + 32768;   short* W5L = W5H + 32768;
    short* W6H = W5L + 32768;   short* W6L = W6H + 16384;

    histo_kernel<<<nblk, 256, 0, stream>>>(rm, hist);
    scan_kernel<<<1, 256, 0, stream>>>(hist, base, meta);
    scatter_kernel<<<nblk, 256, 0, stream>>>(rm, base, perm);
    prep_kernel<<<1088, 256, 0, stream>>>(W1, W2, W3, W4, W5, W6,
                                          W1H, W1L, W2H, W2L, W3H, W3L,
                                          W4H, W4L, W5H, W5L, W6H, W6L);
    mlp_mfma<<<B / 64 + NE, 256, 0, stream>>>(x, perm, meta,
                                              W1H, W1L, W2H, W2L, W3H, W3L,
                                              W4H, W4L, W5H, W5L, W6H, W6L,
                                              b1, b2, b3, b4, b5, b6, out);
}

// Round 3
// 148.416 us; speedup vs baseline: 1.9014x; 1.0373x over previous
//
#include <hip/hip_runtime.h>
#include <hip/hip_bf16.h>

// DeepQNetwork MoE as a sorted grouped GEMM with split-bf16 MFMA.
// 3 launches: prep_histo (weight frags + per-block expert histogram)
//          -> scan_scatter (redundant per-block shfl scan + ballot-rank scatter)
//          -> mlp_mfma (64 rows/block, 1 expert/block, 3-term split bf16 MFMA)

#define NE   8
#define DIM  256
#define HID  64
#define NA   18

typedef __attribute__((ext_vector_type(8))) short short8;
typedef __attribute__((ext_vector_type(4))) float f32x4;
#define MFMA __builtin_amdgcn_mfma_f32_16x16x32_bf16

// ---------- bf16 split helpers ----------
__device__ __forceinline__ unsigned short f2bf(float f) {     // RNE, scalar (prep only)
    unsigned u = __builtin_bit_cast(unsigned, f);
    u += 0x7fff + ((u >> 16) & 1);
    return (unsigned short)(u >> 16);
}
__device__ __forceinline__ float bf2f(unsigned short h) {
    unsigned u = ((unsigned)h) << 16;
    return __builtin_bit_cast(float, u);
}
// vectorized split: compiler emits v_cvt_pk_bf16_f32 for __float22bfloat162_rn
__device__ __forceinline__ void split8v(const float* xs, short8& hi, short8& lo) {
    float back[8];
    #pragma unroll
    for (int p = 0; p < 4; ++p) {
        __hip_bfloat162 h2 = __float22bfloat162_rn(make_float2(xs[2*p], xs[2*p+1]));
        hi[2*p]   = (short)__builtin_bit_cast(unsigned short, h2.x);
        hi[2*p+1] = (short)__builtin_bit_cast(unsigned short, h2.y);
        float2 b2 = __bfloat1622float2(h2);
        back[2*p] = b2.x; back[2*p+1] = b2.y;
    }
    #pragma unroll
    for (int p = 0; p < 4; ++p) {
        __hip_bfloat162 l2 = __float22bfloat162_rn(
            make_float2(xs[2*p] - back[2*p], xs[2*p+1] - back[2*p+1]));
        lo[2*p]   = (short)__builtin_bit_cast(unsigned short, l2.x);
        lo[2*p+1] = (short)__builtin_bit_cast(unsigned short, l2.y);
    }
}

// ---------- kernel 1: weight fragmentation + expert histogram (fused) ----------
// prep: blocks [0, 1088)   histo: blocks [1088, 1344)
// frag idx within expert-layer: ((ks*NNT + nt)*64 + lane)*8 + j
// value = W[k][n],  k = ks*32 + (lane>>4)*8 + j,  n = nt*16 + (lane&15)
__global__ __launch_bounds__(256) void prep_histo(
    const float* __restrict__ W1, const float* __restrict__ W2,
    const float* __restrict__ W3, const float* __restrict__ W4,
    const float* __restrict__ W5, const float* __restrict__ W6,
    short* __restrict__ W1H, short* __restrict__ W1L,
    short* __restrict__ W2H, short* __restrict__ W2L,
    short* __restrict__ W3H, short* __restrict__ W3L,
    short* __restrict__ W4H, short* __restrict__ W4L,
    short* __restrict__ W5H, short* __restrict__ W5L,
    short* __restrict__ W6H, short* __restrict__ W6L,
    const int* __restrict__ rm, int* __restrict__ hist) {
    const int bid = blockIdx.x;
    if (bid >= 1088) {                        // ---- histogram part ----
        __shared__ int wch[4][NE];
        const int blk = bid - 1088;
        const int t = threadIdx.x, w = t >> 6, l = t & 63;
        const int e = rm[blk * 256 + t];
        #pragma unroll
        for (int q = 0; q < NE; ++q) {
            unsigned long long m = __ballot(e == q);
            if (l == 0) wch[w][q] = __popcll(m);
        }
        __syncthreads();
        if (t < NE) hist[blk * NE + t] = wch[0][t] + wch[1][t] + wch[2][t] + wch[3][t];
        return;
    }
    const int idx = bid * 256 + threadIdx.x;  // ---- prep part ----
    float v; short* H; short* L; int sidx;
    if (idx < 131072) {                       // W1: 8e x 8ks x 4nt x 64l x 8j
        int e = idx >> 14, r = idx & 16383;
        int ks = r >> 11, nt = (r >> 9) & 3, l = (r >> 3) & 63, j = r & 7;
        int k = ks * 32 + ((l >> 4) << 3) + j, n = (nt << 4) + (l & 15);
        v = W1[(e * DIM + k) * HID + n];
        H = W1H; L = W1L; sidx = idx;
    } else if (idx < 131072 + 4 * 32768) {    // W2..W5: 8e x 2ks x 4nt x 64l x 8j
        int layer = (idx - 131072) >> 15;
        int local = (idx - 131072) & 32767;
        int e = local >> 12, r = local & 4095;
        int ks = r >> 11, nt = (r >> 9) & 3, l = (r >> 3) & 63, j = r & 7;
        int k = ks * 32 + ((l >> 4) << 3) + j, n = (nt << 4) + (l & 15);
        const float* W = (layer == 0) ? W2 : (layer == 1) ? W3 : (layer == 2) ? W4 : W5;
        v = W[(e * HID + k) * HID + n];
        H = (layer == 0) ? W2H : (layer == 1) ? W3H : (layer == 2) ? W4H : W5H;
        L = (layer == 0) ? W2L : (layer == 1) ? W3L : (layer == 2) ? W4L : W5L;
        sidx = local;
    } else {                                  // W6: 8e x 2ks x 2nt x 64l x 8j (N pad->32)
        int local = idx - (131072 + 4 * 32768);
        int e = local >> 11, r = local & 2047;
        int ks = r >> 10, nt = (r >> 9) & 1, l = (r >> 3) & 63, j = r & 7;
        int k = ks * 32 + ((l >> 4) << 3) + j, n = (nt << 4) + (l & 15);
        v = (n < NA) ? W6[(e * HID + k) * NA + n] : 0.0f;
        H = W6H; L = W6L; sidx = local;
    }
    unsigned short h = f2bf(v);
    H[sidx] = (short)h;
    L[sidx] = (short)f2bf(v - bf2f(h));
}

// ---------- kernel 2: fused scan + scatter ----------
// 256 blocks x 512 threads. Each block redundantly scans the 256x8 histogram
// (8 waves, one expert per wave, 4 values/lane + __shfl_up wave scan), then
// ballot-rank scatters its own 256 rows into perm. Block 0 writes meta.
// meta[0..7]=counts  meta[8..16]=expertStart  meta[17..25]=tileStart
__global__ __launch_bounds__(512) void scan_scatter(const int* __restrict__ rm,
                                                    const int* __restrict__ hist,
                                                    int* __restrict__ perm,
                                                    int* __restrict__ meta) {
    __shared__ int sbuf[NE][256];
    __shared__ int wc[8][NE];
    __shared__ int wb2[4][NE];
    __shared__ int baseE[NE];
    const int t = threadIdx.x, w = t >> 6, l = t & 63;
    const int myblk = blockIdx.x;

    // --- scan: wave w handles expert w ---
    {
        int v0 = hist[(l * 4 + 0) * NE + w];
        int v1 = hist[(l * 4 + 1) * NE + w];
        int v2 = hist[(l * 4 + 2) * NE + w];
        int v3 = hist[(l * 4 + 3) * NE + w];
        v1 += v0; v2 += v1; v3 += v2;
        int s = v3;
        #pragma unroll
        for (int off = 1; off < 64; off <<= 1) {
            int u = __shfl_up(s, off);
            if (l >= off) s += u;
        }
        const int ex = s - v3;
        sbuf[w][l * 4 + 0] = ex + v0;
        sbuf[w][l * 4 + 1] = ex + v1;
        sbuf[w][l * 4 + 2] = ex + v2;
        sbuf[w][l * 4 + 3] = ex + v3;
    }
    __syncthreads();
    if (t < NE) {
        int es = 0;
        for (int q = 0; q < t; ++q) es += sbuf[q][255];
        baseE[t] = es + (myblk ? sbuf[t][myblk - 1] : 0);
    }
    if (myblk == 0 && t == 0) {
        int es = 0, ts = 0;
        meta[8] = 0; meta[17] = 0;
        for (int e = 0; e < NE; ++e) {
            int c = sbuf[e][255];
            meta[e] = c;
            es += c; meta[8 + e + 1] = es;
            ts += (c + 63) >> 6; meta[17 + e + 1] = ts;
        }
    }
    // --- scatter: rows handled by threads 0..255 (waves 4..7 idle but in-barrier) ---
    const int i = myblk * 256 + t;
    const int e_row = (t < 256) ? rm[i] : -1;
    const unsigned long long ltm = (1ull << l) - 1ull;
    int rank = 0;
    #pragma unroll
    for (int q = 0; q < NE; ++q) {
        unsigned long long m = __ballot(e_row == q);
        if (e_row == q) rank = __popcll(m & ltm);
        if (l == 0) wc[w][q] = __popcll(m);
    }
    __syncthreads();
    if (t < 32) {
        int ww = t >> 3, q = t & 7;
        int b = baseE[q];
        for (int p = 0; p < ww; ++p) b += wc[p][q];
        wb2[ww][q] = b;
    }
    __syncthreads();
    if (t < 256) perm[wb2[w][e_row] + rank] = i;
}

// ---------- kernel 3: MFMA MLP ----------
// 3 independent accumulator banks (hi*hi, lo*hi, hi*lo) -> 3x the MFMA ILP;
// merged at finish. B-frags staged through register arrays per ks.
template <int NT>
__device__ __forceinline__ void gemm_k64(const float* hsrc, int l,
                                         const short* __restrict__ WH,
                                         const short* __restrict__ WL,
                                         f32x4* a0, f32x4* a1, f32x4* a2) {
    const int lg = l >> 4, lr = l & 15;
    #pragma unroll
    for (int ks = 0; ks < 2; ++ks) {
        const float* ap = hsrc + lr * 68 + ks * 32 + lg * 8;
        float4 v0 = *(const float4*)(ap);
        float4 v1 = *(const float4*)(ap + 4);
        float xs[8] = {v0.x, v0.y, v0.z, v0.w, v1.x, v1.y, v1.z, v1.w};
        short8 ahi, alo; split8v(xs, ahi, alo);
        short8 bh[NT], bl[NT];
        #pragma unroll
        for (int nt = 0; nt < NT; ++nt) {
            bh[nt] = *(const short8*)(WH + ((ks * NT + nt) * 64 + l) * 8);
            bl[nt] = *(const short8*)(WL + ((ks * NT + nt) * 64 + l) * 8);
        }
        #pragma unroll
        for (int nt = 0; nt < NT; ++nt) {
            a0[nt] = MFMA(ahi, bh[nt], a0[nt], 0, 0, 0);
            a1[nt] = MFMA(alo, bh[nt], a1[nt], 0, 0, 0);
            a2[nt] = MFMA(ahi, bl[nt], a2[nt], 0, 0, 0);
        }
    }
}

template <int NT, bool RELU>
__device__ __forceinline__ void finish_to_lds(float* hdst, int l,
                                              const float* __restrict__ bias,
                                              f32x4* a0, f32x4* a1, f32x4* a2) {
    const int lg = l >> 4, lr = l & 15;
    #pragma unroll
    for (int nt = 0; nt < NT; ++nt) {
        float bv = bias[nt * 16 + lr];
        #pragma unroll
        for (int r = 0; r < 4; ++r) {
            float v = (a0[nt][r] + a1[nt][r]) + (a2[nt][r] + bv);
            if (RELU) v = fmaxf(v, 0.0f);
            hdst[(lg * 4 + r) * 68 + nt * 16 + lr] = v;   // D: row=(l>>4)*4+r, col=l&15
        }
    }
}

__global__ __launch_bounds__(256, 4) void mlp_mfma(
    const float* __restrict__ x, const int* __restrict__ perm,
    const int* __restrict__ meta,
    const short* __restrict__ W1H, const short* __restrict__ W1L,
    const short* __restrict__ W2H, const short* __restrict__ W2L,
    const short* __restrict__ W3H, const short* __restrict__ W3L,
    const short* __restrict__ W4H, const short* __restrict__ W4L,
    const short* __restrict__ W5H, const short* __restrict__ W5L,
    const short* __restrict__ W6H, const short* __restrict__ W6L,
    const float* __restrict__ b1, const float* __restrict__ b2,
    const float* __restrict__ b3, const float* __restrict__ b4,
    const float* __restrict__ b5, const float* __restrict__ b6,
    float* __restrict__ out) {
    __shared__ __align__(16) float hbuf[4][16][68];
    const int blk = blockIdx.x;
    if (blk >= meta[17 + NE]) return;
    int e = 0;
    #pragma unroll 1
    while (blk >= meta[17 + e + 1]) ++e;
    const int lt = blk - meta[17 + e];
    const int cnt = meta[e];
    const int pbase = meta[8 + e];
    const int t = threadIdx.x, w = t >> 6, l = t & 63;
    const int lg = l >> 4, lr = l & 15;
    const int li = lt * 64 + w * 16 + lr;
    const int row = perm[pbase + min(li, cnt - 1)];
    float* hw = &hbuf[w][0][0];
    const f32x4 zero = {0.0f, 0.0f, 0.0f, 0.0f};

    // ---- layer 1: x[row][256] @ W1 -> h[16][64] ----
    {
        f32x4 a0[4] = {zero, zero, zero, zero};
        f32x4 a1[4] = {zero, zero, zero, zero};
        f32x4 a2[4] = {zero, zero, zero, zero};
        const float* xr = x + (size_t)row * DIM + lg * 8;
        const short* WHp = W1H + (size_t)e * 32 * 512 + l * 8;
        const short* WLp = W1L + (size_t)e * 32 * 512 + l * 8;
        #pragma unroll
        for (int ks = 0; ks < 8; ++ks) {
            float4 v0 = *(const float4*)(xr + ks * 32);
            float4 v1 = *(const float4*)(xr + ks * 32 + 4);
            float xs[8] = {v0.x, v0.y, v0.z, v0.w, v1.x, v1.y, v1.z, v1.w};
            short8 ahi, alo; split8v(xs, ahi, alo);
            short8 bh[4], bl[4];
            #pragma unroll
            for (int nt = 0; nt < 4; ++nt) {
                bh[nt] = *(const short8*)(WHp + (ks * 4 + nt) * 512);
                bl[nt] = *(const short8*)(WLp + (ks * 4 + nt) * 512);
            }
            #pragma unroll
            for (int nt = 0; nt < 4; ++nt) {
                a0[nt] = MFMA(ahi, bh[nt], a0[nt], 0, 0, 0);
                a1[nt] = MFMA(alo, bh[nt], a1[nt], 0, 0, 0);
                a2[nt] = MFMA(ahi, bl[nt], a2[nt], 0, 0, 0);
            }
        }
        finish_to_lds<4, true>(hw, l, b1 + e * HID, a0, a1, a2);
    }
    // ---- layers 2..5 ----
    #define HIDDEN(WH_, WL_, bias_)                                   \
    {                                                                 \
        f32x4 a0[4] = {zero, zero, zero, zero};                       \
        f32x4 a1[4] = {zero, zero, zero, zero};                       \
        f32x4 a2[4] = {zero, zero, zero, zero};                       \
        gemm_k64<4>(hw, l, WH_ + e * 8 * 512, WL_ + e * 8 * 512,      \
                    a0, a1, a2);                                      \
        finish_to_lds<4, true>(hw, l, bias_ + e * HID, a0, a1, a2);   \
    }
    HIDDEN(W2H, W2L, b2)
    HIDDEN(W3H, W3L, b3)
    HIDDEN(W4H, W4L, b4)
    HIDDEN(W5H, W5L, b5)
    #undef HIDDEN
    // ---- layer 6 + scatter store ----
    {
        f32x4 a0[2] = {zero, zero};
        f32x4 a1[2] = {zero, zero};
        f32x4 a2[2] = {zero, zero};
        gemm_k64<2>(hw, l, W6H + e * 4 * 512, W6L + e * 4 * 512, a0, a1, a2);
        const float* b6p = b6 + e * NA;
        #pragma unroll
        for (int r = 0; r < 4; ++r) {
            const int drow = lg * 4 + r;
            const int rs = __shfl(row, drow, 64);
            const bool valid = (lt * 64 + w * 16 + drow) < cnt;
            #pragma unroll
            for (int nt = 0; nt < 2; ++nt) {
                const int col = nt * 16 + lr;
                if (valid && col < NA)
                    out[(size_t)rs * NA + col] = (a0[nt][r] + a1[nt][r]) + (a2[nt][r] + b6p[col]);
            }
        }
    }
}

extern "C" void kernel_launch(void* const* d_in, const int* in_sizes, int n_in,
                              void* d_out, int out_size, void* d_ws, size_t ws_size,
                              hipStream_t stream) {
    const float* x  = (const float*)d_in[0];
    const int*   rm = (const int*)d_in[1];
    const float* W1 = (const float*)d_in[2];   const float* b1 = (const float*)d_in[3];
    const float* W2 = (const float*)d_in[4];   const float* b2 = (const float*)d_in[5];
    const float* W3 = (const float*)d_in[6];   const float* b3 = (const float*)d_in[7];
    const float* W4 = (const float*)d_in[8];   const float* b4 = (const float*)d_in[9];
    const float* W5 = (const float*)d_in[10];  const float* b5 = (const float*)d_in[11];
    const float* W6 = (const float*)d_in[12];  const float* b6 = (const float*)d_in[13];
    float* out = (float*)d_out;

    const int B = in_sizes[1];                 // 65536
    const int nblk = B / 256;                  // 256

    // ws layout:
    int* hist = (int*)d_ws;                    // nblk*8
    int* meta = hist + nblk * NE;              // 32
    int* perm = meta + 32;                     // B
    short* W1H = (short*)(perm + B);           // 131072 each
    short* W1L = W1H + 131072;
    short* W2H = W1L + 131072;  short* W2L = W2H + 32768;
    short* W3H = W2L + 32768;   short* W3L = W3H + 32768;
    short* W4H = W3L + 32768;   short* W4L = W4H + 32768;
    short* W5H = W4L + 32768;   short* W5L = W5H + 32768;
    short* W6H = W5L + 32768;   short* W6L = W6H + 16384;

    prep_histo<<<1088 + nblk, 256, 0, stream>>>(W1, W2, W3, W4, W5, W6,
                                                W1H, W1L, W2H, W2L, W3H, W3L,
                                                W4H, W4L, W5H, W5L, W6H, W6L,
                                                rm, hist);
    scan_scatter<<<nblk, 512, 0, stream>>>(rm, hist, perm, meta);
    mlp_mfma<<<B / 64 + NE, 256, 0, stream>>>(x, perm, meta,
                                              W1H, W1L, W2H, W2L, W3H, W3L,
                                              W4H, W4L, W5H, W5L, W6H, W6L,
                                              b1, b2, b3, b4, b5, b6, out);
}